// Round 11
// baseline (1055.427 us; speedup 1.0000x reference)
//
#include <hip/hip_runtime.h>
#include <stdint.h>

// Problem constants
#define BATCH 4096
#define DIMD  256
#define DIMH  1024
#define NEEL  10485760   // E elements per stage: 10*4096*256

typedef __attribute__((ext_vector_type(8))) short short8;
typedef __attribute__((ext_vector_type(4))) float float4v;

struct Keys4 { uint32_t a[4]; uint32_t b[4]; };

// ---------------- threefry2x32 (JAX-compatible, 20 rounds) ----------------
__host__ __device__ static inline uint32_t rotl32(uint32_t v, int r) {
#ifdef __HIP_DEVICE_COMPILE__
    return __builtin_amdgcn_alignbit(v, v, 32 - r);   // 1-inst funnel rotate
#else
    return (v << r) | (v >> (32 - r));
#endif
}

__host__ __device__ static inline void tf2x32(uint32_t k0, uint32_t k1,
                                              uint32_t c0, uint32_t c1,
                                              uint32_t& o0, uint32_t& o1) {
    uint32_t ks0 = k0, ks1 = k1, ks2 = k0 ^ k1 ^ 0x1BD11BDAu;
    uint32_t x0 = c0 + ks0, x1 = c1 + ks1;
#define TF_R4(a, b, c, d)                                   \
    x0 += x1; x1 = rotl32(x1, a); x1 ^= x0;                 \
    x0 += x1; x1 = rotl32(x1, b); x1 ^= x0;                 \
    x0 += x1; x1 = rotl32(x1, c); x1 ^= x0;                 \
    x0 += x1; x1 = rotl32(x1, d); x1 ^= x0;
    TF_R4(13, 15, 26, 6)  x0 += ks1; x1 += ks2 + 1u;
    TF_R4(17, 29, 16, 24) x0 += ks2; x1 += ks0 + 2u;
    TF_R4(13, 15, 26, 6)  x0 += ks0; x1 += ks1 + 3u;
    TF_R4(17, 29, 16, 24) x0 += ks1; x1 += ks2 + 4u;
    TF_R4(13, 15, 26, 6)  x0 += ks2; x1 += ks0 + 5u;
#undef TF_R4
    o0 = x0; o1 = x1;
}

// float -> bf16 (round-to-nearest-even), bit pattern in a short
__device__ static inline short f2bf(float f) {
    uint32_t u = __float_as_uint(f);
    uint32_t r = (u + 0x7FFFu + ((u >> 16) & 1u)) >> 16;
    return (short)r;
}

// ---------------- Prep (fused): W1T, W2B, W2T, Zb0, dv=0, E0 bf16 ---------
// Flat index ranges. Stage-0 Rademacher: E0[j] = bit(j) ? +1 : -1 (bf16),
// bit[j] = (y0^y1)&1 of tf(k2_0, (0, j)) — JAX partitionable threefry.
__global__ __launch_bounds__(256) void k_prep(
    const float* __restrict__ x,  const float* __restrict__ W1,
    const float* __restrict__ W2, short* __restrict__ W1T,
    short* __restrict__ W2B, short* __restrict__ W2T,
    short* __restrict__ zb, float* __restrict__ dv,
    short* __restrict__ E0, uint32_t ek0, uint32_t ek1)
{
    const int idx = blockIdx.x * 256 + threadIdx.x;
    if (idx < 262144) {                       // W1T[n][d] = bf16(W1[d][n])
        const int n = idx >> 8, d = idx & 255;
        W1T[idx] = f2bf(W1[d * DIMH + n]);
    } else if (idx < 524288) {                // W2B = bf16(W2) row-major
        const int i = idx - 262144;
        W2B[i] = f2bf(W2[i]);
    } else if (idx < 786432) {                // W2T[d][k] = bf16(W2[k][d])
        const int i = idx - 524288;
        const int d = i >> 10, k = i & 1023;
        W2T[i] = f2bf(W2[k * DIMD + d]);
    } else if (idx < 1835008) {               // zb0 = bf16(x)
        const int i = idx - 786432;
        zb[i] = f2bf(x[i]);
    } else if (idx < 1851392) {               // dv = 0 (4*4096 floats)
        dv[idx - 1835008] = 0.0f;
    } else {                                  // E0: 10.49M bf16 Rademacher
        const uint32_t j = (uint32_t)(idx - 1851392);
        uint32_t y0, y1;
        tf2x32(ek0, ek1, 0u, j, y0, y1);
        E0[j] = ((y0 ^ y1) & 1u) ? (short)0x3F80 : (short)0xBF80u;
    }
}

// ---------------- Fused K1+K3: h-tile + probes (global-E, barrier-free) ---
// Grid (16 n-tiles, 64 batch-tiles) = 1024 blocks. 256 thr = 4 waves; wave
// owns one 16-wide n-subtile: n = nt*64 + wave*16 + col.
// Phase 1 (h): C = Zb @ W1T^T; tanh; writes hb; keeps s = 1-h^2 in regs
//   (MFMA C-layout of h == the sreg layout the probe loop needs).
// Probe loop: A-frags read DIRECTLY from global bf16 E (written by the
//   previous stage) — no LDS tile, no expansion, no __syncthreads. The 16
//   nt-blocks per y-row share each 32 KB E tile in L2. Egen for the NEXT
//   stage (40 ciphers/thread -> 40 bf16 stores) interleaved 1 per
//   (probe,ms) so its VALU sits adjacent to MFMA issue.
__global__ __launch_bounds__(256) void k_pre_div(
    const short* __restrict__ Zb, const short* __restrict__ W1T,
    const short* __restrict__ W2B, const float* __restrict__ W1,
    const float* __restrict__ b1, float tval,
    const short* __restrict__ Ecur, short* __restrict__ h_bf,
    float* __restrict__ divacc,
    short* __restrict__ Enext, uint32_t nk0, uint32_t nk1, int do_egen)
{
    const int t = threadIdx.x;
    const int nt = blockIdx.x;         // fastest-varying: y-row blocks share E in L2
    const int b0 = blockIdx.y * 64;
    const int wave = t >> 6, lane = t & 63;
    const int col = lane & 15, kq = lane >> 4;
    const int n = nt * 64 + wave * 16 + col;

    // B-fragments, once per kernel
    short8 bufr[8], bvfr[8];
#pragma unroll
    for (int ks = 0; ks < 8; ++ks) {
        bufr[ks] = *(const short8*)&W1T[n * DIMD + ks * 32 + kq * 8];
        bvfr[ks] = *(const short8*)&W2B[n * DIMD + ks * 32 + kq * 8];
    }

    // ---- Phase 1: h = tanh(Zb @ W1T^T + t*W1[256] + b1) ----
    float sreg[4][4];
    const float add = tval * W1[DIMD * DIMH + n] + b1[n];
#pragma unroll
    for (int ms = 0; ms < 4; ++ms) {
        float4v acc = {0.f, 0.f, 0.f, 0.f};
#pragma unroll
        for (int ks = 0; ks < 8; ++ks) {
            short8 af = *(const short8*)&Zb[(b0 + ms * 16 + col) * DIMD + ks * 32 + kq * 8];
            acc = __builtin_amdgcn_mfma_f32_16x16x32_bf16(af, bufr[ks], acc, 0, 0, 0);
        }
        // C layout: col = lane&15, row = kq*4 + r (verified m89/m91)
#pragma unroll
        for (int r = 0; r < 4; ++r) {
            float hv = tanhf(acc[r] + add);
            h_bf[(b0 + ms * 16 + kq * 4 + r) * DIMH + n] = f2bf(hv);
            sreg[ms][r] = 1.0f - hv * hv;
        }
    }

    float rowacc[4][4];
#pragma unroll
    for (int a = 0; a < 4; ++a)
#pragma unroll
        for (int r = 0; r < 4; ++r) rowacc[a][r] = 0.0f;

    // next-stage egen share: block bflat covers j in [bflat*10240, +10240)
    const uint32_t bflat = (uint32_t)(blockIdx.y * 16 + blockIdx.x);
    const uint32_t jbase = bflat * 10240u + (uint32_t)t;

    // ---- Probe loop: barrier-free, A-frags from global E ----
#pragma unroll 1
    for (int probe = 0; probe < 10; ++probe) {
        const short* Ep = Ecur + (size_t)probe * (BATCH * DIMD) + (size_t)b0 * DIMD;
#pragma unroll
        for (int ms = 0; ms < 4; ++ms) {
            if (do_egen) {                       // 1 cipher per (probe,ms) = 40 total
                uint32_t j = jbase + (uint32_t)(probe * 4 + ms) * 256u;
                uint32_t y0, y1;
                tf2x32(nk0, nk1, 0u, j, y0, y1);
                Enext[j] = ((y0 ^ y1) & 1u) ? (short)0x3F80 : (short)0xBF80u;
            }
            const short* arow = Ep + (ms * 16 + col) * DIMD + kq * 8;
            float4v u = {0.f, 0.f, 0.f, 0.f}, v = {0.f, 0.f, 0.f, 0.f};
#pragma unroll
            for (int ks = 0; ks < 8; ++ks) {
                short8 af = *(const short8*)&arow[ks * 32];
                u = __builtin_amdgcn_mfma_f32_16x16x32_bf16(af, bufr[ks], u, 0, 0, 0);
                v = __builtin_amdgcn_mfma_f32_16x16x32_bf16(af, bvfr[ks], v, 0, 0, 0);
            }
#pragma unroll
            for (int r = 0; r < 4; ++r)
                rowacc[ms][r] += u[r] * sreg[ms][r] * v[r];
        }
    }

#pragma unroll
    for (int ms = 0; ms < 4; ++ms) {
#pragma unroll
        for (int r = 0; r < 4; ++r) {
            float p = rowacc[ms][r];
            p += __shfl_xor(p, 1, 64);
            p += __shfl_xor(p, 2, 64);
            p += __shfl_xor(p, 4, 64);
            p += __shfl_xor(p, 8, 64);
            rowacc[ms][r] = p;
        }
    }
    if (col == 0) {
#pragma unroll
        for (int ms = 0; ms < 4; ++ms)
#pragma unroll
            for (int r = 0; r < 4; ++r)
                atomicAdd(&divacc[b0 + ms * 16 + kq * 4 + r], rowacc[ms][r] * 0.1f);
    }
}

// ---------------- K2: fz = Hb @ W2 + b2; rksum += cw*fz; fuse Zb_next -----
// MFMA 16x16x32, K=1024 pipelined. Block 256 thr = 4 waves; wave = 16 rows
// x 64 cols (waves tile N=256). Grid = 4096/16 = 256.
// rksum accumulates the RK4 combination (cw = 1,2,2,1); stage 0 stores
// (first=1, no read — ws is poison-initialized), stages 1-3 read-add-store.
__global__ __launch_bounds__(256) void k_fz2(
    const short* __restrict__ Hb, const short* __restrict__ W2T,
    const float* __restrict__ b2, const float* __restrict__ x,
    float* __restrict__ rksum, float cw, int first,
    float cnext, int write_zb, short* __restrict__ zb)
{
    const int t = threadIdx.x;
    const int wave = t >> 6, lane = t & 63;
    const int col = lane & 15, kq = lane >> 4;
    const int m0 = blockIdx.x * 16;
    const int n0 = wave * 64;

    float4v acc[4];
#pragma unroll
    for (int ns = 0; ns < 4; ++ns) acc[ns] = (float4v){0.f, 0.f, 0.f, 0.f};

    const short* ap = &Hb[(m0 + col) * DIMH + kq * 8];
    short8 a_cur = *(const short8*)ap;
    short8 b_cur[4];
#pragma unroll
    for (int ns = 0; ns < 4; ++ns)
        b_cur[ns] = *(const short8*)&W2T[(n0 + ns * 16 + col) * DIMH + kq * 8];

    for (int ks = 0; ks < 31; ++ks) {
        short8 a_nxt = *(const short8*)&ap[(ks + 1) * 32];
        short8 b_nxt[4];
#pragma unroll
        for (int ns = 0; ns < 4; ++ns)
            b_nxt[ns] = *(const short8*)&W2T[(n0 + ns * 16 + col) * DIMH + (ks + 1) * 32 + kq * 8];
#pragma unroll
        for (int ns = 0; ns < 4; ++ns)
            acc[ns] = __builtin_amdgcn_mfma_f32_16x16x32_bf16(a_cur, b_cur[ns], acc[ns], 0, 0, 0);
        a_cur = a_nxt;
#pragma unroll
        for (int ns = 0; ns < 4; ++ns) b_cur[ns] = b_nxt[ns];
    }
#pragma unroll
    for (int ns = 0; ns < 4; ++ns)
        acc[ns] = __builtin_amdgcn_mfma_f32_16x16x32_bf16(a_cur, b_cur[ns], acc[ns], 0, 0, 0);

#pragma unroll
    for (int ns = 0; ns < 4; ++ns) {
        const int n = n0 + ns * 16 + col;
        const float bias = b2[n];
#pragma unroll
        for (int r = 0; r < 4; ++r) {
            const int m = m0 + kq * 4 + r;
            const int o = m * DIMD + n;
            const float val = acc[ns][r] + bias;
            const float contrib = cw * val;
            rksum[o] = first ? contrib : (rksum[o] + contrib);
            if (write_zb)
                zb[o] = f2bf(x[o] + cnext * val);
        }
    }
}

// ---------------- K4: RK4 combine + output --------------------------------
__global__ __launch_bounds__(256) void k_out(
    const float* __restrict__ x, const float* __restrict__ rksum,
    const float* __restrict__ divacc, float* __restrict__ out)
{
    const int idx = blockIdx.x * 256 + threadIdx.x;
    const int TOT = BATCH * (DIMD + 1);
    if (idx >= TOT) return;
    const int b = idx / (DIMD + 1);
    const int c = idx - b * (DIMD + 1);
    const float sixth = 1.0f / 6.0f;
    if (c < DIMD) {
        float xv = x[b * DIMD + c];
        out[idx] = xv;
        out[TOT + idx] = xv + rksum[b * DIMD + c] * sixth;
    } else {
        float d1 = divacc[b];
        float d2 = divacc[BATCH + b];
        float d3 = divacc[2 * BATCH + b];
        float d4 = divacc[3 * BATCH + b];
        out[idx] = 0.0f;
        out[TOT + idx] = -(d1 + 2.0f * d2 + 2.0f * d3 + d4) * sixth;
    }
}

// ---------------- launch ---------------------------------------------------
extern "C" void kernel_launch(void* const* d_in, const int* in_sizes, int n_in,
                              void* d_out, int out_size, void* d_ws, size_t ws_size,
                              hipStream_t stream) {
    const float* x  = (const float*)d_in[0];
    const float* W1 = (const float*)d_in[1];
    const float* b1 = (const float*)d_in[2];
    const float* W2 = (const float*)d_in[3];
    const float* b2 = (const float*)d_in[4];
    float* out = (float*)d_out;

    char* ws = (char*)d_ws;
    short* hb    = (short*)(ws);                   // 8 MiB
    float* rksum = (float*)(ws + 8388608);         // 4 MiB
    short* zb    = (short*)(ws + 12582912);        // 2 MiB
    short* w1t   = (short*)(ws + 14680064);        // 512 KiB
    short* w2b   = (short*)(ws + 15204352);        // 512 KiB
    short* w2t   = (short*)(ws + 15728640);        // 512 KiB
    float* dv    = (float*)(ws + 16252928);        // 64 KiB
    short* e0    = (short*)(ws + 16318464);        // 20 MiB (bf16 E, ping)
    short* e1    = (short*)(ws + 37289984);        // 20 MiB (bf16 E, pong)
    // total 58261504 B ~= 55.6 MiB

    // Host-side threefry key derivation (partitionable semantics):
    //   fk_i = tf((0,42),(0,i));  k2_i = tf(fk_i,(0,1))
    Keys4 keys;
    for (uint32_t i = 0; i < 4; ++i) {
        uint32_t f0, f1, g0, g1;
        tf2x32(0u, 42u, 0u, i, f0, f1);
        tf2x32(f0, f1, 0u, 1u, g0, g1);
        keys.a[i] = g0;
        keys.b[i] = g1;
    }

    // 1851392 prep items + 10485760 E0 items = 12337152 = 48192*256
    k_prep<<<48192, 256, 0, stream>>>(x, W1, W2, w1t, w2b, w2t, zb, dv,
                                      e0, keys.a[0], keys.b[0]);

    const float tvals[4] = {0.0f, 0.5f, 0.5f, 1.0f};
    const float cnext[4] = {0.5f, 0.5f, 1.0f, 0.0f};  // Zb_{s+1} = x + cnext*fz_s
    const float cw[4]    = {1.0f, 2.0f, 2.0f, 1.0f};  // RK4 weights
    for (int s = 0; s < 4; ++s) {
        const int last = (s == 3);
        short* ecur = (s & 1) ? e1 : e0;
        short* enxt = (s & 1) ? e0 : e1;
        k_pre_div<<<dim3(16, 64), 256, 0, stream>>>(
            zb, w1t, w2b, W1, b1, tvals[s], ecur,
            hb, dv + (size_t)s * BATCH,
            enxt, last ? 0u : keys.a[s + 1], last ? 0u : keys.b[s + 1],
            last ? 0 : 1);
        k_fz2<<<256, 256, 0, stream>>>(hb, w2t, b2, x, rksum,
                                       cw[s], (s == 0) ? 1 : 0,
                                       cnext[s], (s < 3) ? 1 : 0, zb);
    }
    int tot = BATCH * (DIMD + 1);
    k_out<<<(tot + 255) / 256, 256, 0, stream>>>(x, rksum, dv, out);
}

// Round 12
// 501.198 us; speedup vs baseline: 2.1058x; 2.1058x over previous
//
#include <hip/hip_runtime.h>
#include <stdint.h>

// Problem constants
#define BATCH 4096
#define DIMD  256
#define DIMH  1024
#define NEEL  10485760   // E elements per stage: 10*4096*256
#define NSLOT 1310720    // NEEL/8: short8 slots per stage

typedef __attribute__((ext_vector_type(8))) short short8;
typedef __attribute__((ext_vector_type(4))) float float4v;

struct Keys4 { uint32_t a[4]; uint32_t b[4]; };

// ---------------- threefry2x32 (JAX-compatible, 20 rounds) ----------------
__host__ __device__ static inline uint32_t rotl32(uint32_t v, int r) {
#ifdef __HIP_DEVICE_COMPILE__
    return __builtin_amdgcn_alignbit(v, v, 32 - r);   // 1-inst funnel rotate
#else
    return (v << r) | (v >> (32 - r));
#endif
}

__host__ __device__ static inline void tf2x32(uint32_t k0, uint32_t k1,
                                              uint32_t c0, uint32_t c1,
                                              uint32_t& o0, uint32_t& o1) {
    uint32_t ks0 = k0, ks1 = k1, ks2 = k0 ^ k1 ^ 0x1BD11BDAu;
    uint32_t x0 = c0 + ks0, x1 = c1 + ks1;
#define TF_R4(a, b, c, d)                                   \
    x0 += x1; x1 = rotl32(x1, a); x1 ^= x0;                 \
    x0 += x1; x1 = rotl32(x1, b); x1 ^= x0;                 \
    x0 += x1; x1 = rotl32(x1, c); x1 ^= x0;                 \
    x0 += x1; x1 = rotl32(x1, d); x1 ^= x0;
    TF_R4(13, 15, 26, 6)  x0 += ks1; x1 += ks2 + 1u;
    TF_R4(17, 29, 16, 24) x0 += ks2; x1 += ks0 + 2u;
    TF_R4(13, 15, 26, 6)  x0 += ks0; x1 += ks1 + 3u;
    TF_R4(17, 29, 16, 24) x0 += ks1; x1 += ks2 + 4u;
    TF_R4(13, 15, 26, 6)  x0 += ks2; x1 += ks0 + 5u;
#undef TF_R4
    o0 = x0; o1 = x1;
}

// float -> bf16 (round-to-nearest-even), bit pattern in a short
__device__ static inline short f2bf(float f) {
    uint32_t u = __float_as_uint(f);
    uint32_t r = (u + 0x7FFFu + ((u >> 16) & 1u)) >> 16;
    return (short)r;
}

// E fragment-layout egen: slot q (a short8) covers elements of
//   probe = q>>17, T = (q>>9)&255, ks = (q>>6)&7, lane = q&63, jj = 0..7
//   -> batch row b = T*16 + (lane&15), d = ks*32 + (lane>>4)*8 + jj
//   -> threefry counter j = (probe*4096 + b)*256 + d  (consecutive in jj).
// JAX partitionable threefry: bit = (y0^y1)&1; e = bit ? +1 : -1 (bf16).
__device__ static inline void egen_slot(short* __restrict__ EF, uint32_t q,
                                        uint32_t k0, uint32_t k1) {
    const uint32_t lane = q & 63u;
    const uint32_t ks   = (q >> 6) & 7u;
    const uint32_t T    = (q >> 9) & 255u;
    const uint32_t probe = q >> 17;
    const uint32_t b = T * 16u + (lane & 15u);
    const uint32_t d0 = ks * 32u + (lane >> 4) * 8u;
    const uint32_t jbase = (probe * 4096u + b) * 256u + d0;
    short8 val;
#pragma unroll
    for (int jj = 0; jj < 8; ++jj) {
        uint32_t y0, y1;
        tf2x32(k0, k1, 0u, jbase + (uint32_t)jj, y0, y1);
        val[jj] = ((y0 ^ y1) & 1u) ? (short)0x3F80 : (short)0xBF80u;
    }
    *(short8*)&EF[(size_t)q * 8] = val;
}

// ---------------- Prep (fused): W1T, W2B, W2T, Zb0, dv=0, E0 frags --------
__global__ __launch_bounds__(256) void k_prep(
    const float* __restrict__ x,  const float* __restrict__ W1,
    const float* __restrict__ W2, short* __restrict__ W1T,
    short* __restrict__ W2B, short* __restrict__ W2T,
    short* __restrict__ zb, float* __restrict__ dv,
    short* __restrict__ E0, uint32_t ek0, uint32_t ek1)
{
    const int idx = blockIdx.x * 256 + threadIdx.x;
    if (idx < 262144) {                       // W1T[n][d] = bf16(W1[d][n])
        const int n = idx >> 8, d = idx & 255;
        W1T[idx] = f2bf(W1[d * DIMH + n]);
    } else if (idx < 524288) {                // W2B = bf16(W2) row-major
        const int i = idx - 262144;
        W2B[i] = f2bf(W2[i]);
    } else if (idx < 786432) {                // W2T[d][k] = bf16(W2[k][d])
        const int i = idx - 524288;
        const int d = i >> 10, k = i & 1023;
        W2T[i] = f2bf(W2[k * DIMD + d]);
    } else if (idx < 1835008) {               // zb0 = bf16(x)
        const int i = idx - 786432;
        zb[i] = f2bf(x[i]);
    } else if (idx < 1851392) {               // dv = 0 (4*4096 floats)
        dv[idx - 1835008] = 0.0f;
    } else {                                  // E0 fragments: 1.31M slots
        egen_slot(E0, (uint32_t)(idx - 1851392), ek0, ek1);
    }
}

// ---------------- Fused K1+K3: h-tile + probes (frag-E, barrier-free) -----
// Grid (64 batch-tiles, 16 n-tiles); blockIdx.x = batch tile so the 16
// nt-blocks sharing one E slice get the same flat%8 -> same XCD
// (round-robin heuristic, perf-only). 256 thr = 4 waves; wave owns one
// 16-wide n-subtile: n = nt*64 + wave*16 + col.
// Phase 1 (h): C = Zb @ W1T^T; tanh; writes hb; keeps s = 1-h^2 in regs
//   (MFMA C-layout of h == sreg layout the probe loop needs).
// Probe loop: A-frags are single fully-coalesced 16B/lane loads from the
//   fragment-ordered E buffer (written by the previous stage). No LDS, no
//   __syncthreads — waves free-run. Next stage's E written via egen_slot
//   (5 slots/thread) interleaved every other probe.
__global__ __launch_bounds__(256) void k_pre_div(
    const short* __restrict__ Zb, const short* __restrict__ W1T,
    const short* __restrict__ W2B, const float* __restrict__ W1,
    const float* __restrict__ b1, float tval,
    const short* __restrict__ Ecur, short* __restrict__ h_bf,
    float* __restrict__ divacc,
    short* __restrict__ Enext, uint32_t nk0, uint32_t nk1, int do_egen)
{
    const int t = threadIdx.x;
    const int b0 = blockIdx.x * 64;
    const int nt = blockIdx.y;
    const int wave = t >> 6, lane = t & 63;
    const int col = lane & 15, kq = lane >> 4;
    const int n = nt * 64 + wave * 16 + col;

    // B-fragments, once per kernel
    short8 bufr[8], bvfr[8];
#pragma unroll
    for (int ks = 0; ks < 8; ++ks) {
        bufr[ks] = *(const short8*)&W1T[n * DIMD + ks * 32 + kq * 8];
        bvfr[ks] = *(const short8*)&W2B[n * DIMD + ks * 32 + kq * 8];
    }

    // ---- Phase 1: h = tanh(Zb @ W1T^T + t*W1[256] + b1) ----
    float sreg[4][4];
    const float add = tval * W1[DIMD * DIMH + n] + b1[n];
#pragma unroll
    for (int ms = 0; ms < 4; ++ms) {
        float4v acc = {0.f, 0.f, 0.f, 0.f};
#pragma unroll
        for (int ks = 0; ks < 8; ++ks) {
            short8 af = *(const short8*)&Zb[(b0 + ms * 16 + col) * DIMD + ks * 32 + kq * 8];
            acc = __builtin_amdgcn_mfma_f32_16x16x32_bf16(af, bufr[ks], acc, 0, 0, 0);
        }
        // C layout: col = lane&15, row = kq*4 + r (verified m89/m91)
#pragma unroll
        for (int r = 0; r < 4; ++r) {
            float hv = tanhf(acc[r] + add);
            h_bf[(b0 + ms * 16 + kq * 4 + r) * DIMH + n] = f2bf(hv);
            sreg[ms][r] = 1.0f - hv * hv;
        }
    }

    float rowacc[4][4];
#pragma unroll
    for (int a = 0; a < 4; ++a)
#pragma unroll
        for (int r = 0; r < 4; ++r) rowacc[a][r] = 0.0f;

    const uint32_t bflat = (uint32_t)(blockIdx.y * 64 + blockIdx.x);   // 0..1023
    const uint32_t qbase = bflat * 256u + (uint32_t)t;                 // slot id

    const int Tb = b0 >> 4;   // base m-tile index for this block

    // ---- Probe loop: barrier-free, A-frags from fragment-ordered E ----
#pragma unroll 1
    for (int probe = 0; probe < 10; ++probe) {
        // next-stage egen: 5 slots/thread on even probes
        if (do_egen && (probe & 1) == 0) {
            egen_slot(Enext, qbase + (uint32_t)(probe >> 1) * 262144u, nk0, nk1);
        }
#pragma unroll
        for (int ms = 0; ms < 4; ++ms) {
            // base short8 index: (((probe*256 + Tb+ms)*8 + 0)*64 + lane)
            const short8* ap = (const short8*)Ecur +
                ((size_t)(probe * 256 + Tb + ms) * 8) * 64 + lane;
            short8 af[8];
#pragma unroll
            for (int ks = 0; ks < 8; ++ks) af[ks] = ap[ks * 64];
            float4v u = {0.f, 0.f, 0.f, 0.f}, v = {0.f, 0.f, 0.f, 0.f};
#pragma unroll
            for (int ks = 0; ks < 8; ++ks) {
                u = __builtin_amdgcn_mfma_f32_16x16x32_bf16(af[ks], bufr[ks], u, 0, 0, 0);
                v = __builtin_amdgcn_mfma_f32_16x16x32_bf16(af[ks], bvfr[ks], v, 0, 0, 0);
            }
#pragma unroll
            for (int r = 0; r < 4; ++r)
                rowacc[ms][r] += u[r] * sreg[ms][r] * v[r];
        }
    }

#pragma unroll
    for (int ms = 0; ms < 4; ++ms) {
#pragma unroll
        for (int r = 0; r < 4; ++r) {
            float p = rowacc[ms][r];
            p += __shfl_xor(p, 1, 64);
            p += __shfl_xor(p, 2, 64);
            p += __shfl_xor(p, 4, 64);
            p += __shfl_xor(p, 8, 64);
            rowacc[ms][r] = p;
        }
    }
    if (col == 0) {
#pragma unroll
        for (int ms = 0; ms < 4; ++ms)
#pragma unroll
            for (int r = 0; r < 4; ++r)
                atomicAdd(&divacc[b0 + ms * 16 + kq * 4 + r], rowacc[ms][r] * 0.1f);
    }
}

// ---------------- K2: fz = Hb @ W2 + b2; rksum += cw*fz; fuse Zb_next -----
// MFMA 16x16x32, K=1024 pipelined. Block 256 thr = 4 waves; wave = 16 rows
// x 64 cols (waves tile N=256). Grid = 4096/16 = 256.
__global__ __launch_bounds__(256) void k_fz2(
    const short* __restrict__ Hb, const short* __restrict__ W2T,
    const float* __restrict__ b2, const float* __restrict__ x,
    float* __restrict__ rksum, float cw, int first,
    float cnext, int write_zb, short* __restrict__ zb)
{
    const int t = threadIdx.x;
    const int wave = t >> 6, lane = t & 63;
    const int col = lane & 15, kq = lane >> 4;
    const int m0 = blockIdx.x * 16;
    const int n0 = wave * 64;

    float4v acc[4];
#pragma unroll
    for (int ns = 0; ns < 4; ++ns) acc[ns] = (float4v){0.f, 0.f, 0.f, 0.f};

    const short* ap = &Hb[(m0 + col) * DIMH + kq * 8];
    short8 a_cur = *(const short8*)ap;
    short8 b_cur[4];
#pragma unroll
    for (int ns = 0; ns < 4; ++ns)
        b_cur[ns] = *(const short8*)&W2T[(n0 + ns * 16 + col) * DIMH + kq * 8];

    for (int ks = 0; ks < 31; ++ks) {
        short8 a_nxt = *(const short8*)&ap[(ks + 1) * 32];
        short8 b_nxt[4];
#pragma unroll
        for (int ns = 0; ns < 4; ++ns)
            b_nxt[ns] = *(const short8*)&W2T[(n0 + ns * 16 + col) * DIMH + (ks + 1) * 32 + kq * 8];
#pragma unroll
        for (int ns = 0; ns < 4; ++ns)
            acc[ns] = __builtin_amdgcn_mfma_f32_16x16x32_bf16(a_cur, b_cur[ns], acc[ns], 0, 0, 0);
        a_cur = a_nxt;
#pragma unroll
        for (int ns = 0; ns < 4; ++ns) b_cur[ns] = b_nxt[ns];
    }
#pragma unroll
    for (int ns = 0; ns < 4; ++ns)
        acc[ns] = __builtin_amdgcn_mfma_f32_16x16x32_bf16(a_cur, b_cur[ns], acc[ns], 0, 0, 0);

#pragma unroll
    for (int ns = 0; ns < 4; ++ns) {
        const int n = n0 + ns * 16 + col;
        const float bias = b2[n];
#pragma unroll
        for (int r = 0; r < 4; ++r) {
            const int m = m0 + kq * 4 + r;
            const int o = m * DIMD + n;
            const float val = acc[ns][r] + bias;
            const float contrib = cw * val;
            rksum[o] = first ? contrib : (rksum[o] + contrib);
            if (write_zb)
                zb[o] = f2bf(x[o] + cnext * val);
        }
    }
}

// ---------------- K4: RK4 combine + output --------------------------------
__global__ __launch_bounds__(256) void k_out(
    const float* __restrict__ x, const float* __restrict__ rksum,
    const float* __restrict__ divacc, float* __restrict__ out)
{
    const int idx = blockIdx.x * 256 + threadIdx.x;
    const int TOT = BATCH * (DIMD + 1);
    if (idx >= TOT) return;
    const int b = idx / (DIMD + 1);
    const int c = idx - b * (DIMD + 1);
    const float sixth = 1.0f / 6.0f;
    if (c < DIMD) {
        float xv = x[b * DIMD + c];
        out[idx] = xv;
        out[TOT + idx] = xv + rksum[b * DIMD + c] * sixth;
    } else {
        float d1 = divacc[b];
        float d2 = divacc[BATCH + b];
        float d3 = divacc[2 * BATCH + b];
        float d4 = divacc[3 * BATCH + b];
        out[idx] = 0.0f;
        out[TOT + idx] = -(d1 + 2.0f * d2 + 2.0f * d3 + d4) * sixth;
    }
}

// ---------------- launch ---------------------------------------------------
extern "C" void kernel_launch(void* const* d_in, const int* in_sizes, int n_in,
                              void* d_out, int out_size, void* d_ws, size_t ws_size,
                              hipStream_t stream) {
    const float* x  = (const float*)d_in[0];
    const float* W1 = (const float*)d_in[1];
    const float* b1 = (const float*)d_in[2];
    const float* W2 = (const float*)d_in[3];
    const float* b2 = (const float*)d_in[4];
    float* out = (float*)d_out;

    char* ws = (char*)d_ws;
    short* hb    = (short*)(ws);                   // 8 MiB
    float* rksum = (float*)(ws + 8388608);         // 4 MiB
    short* zb    = (short*)(ws + 12582912);        // 2 MiB
    short* w1t   = (short*)(ws + 14680064);        // 512 KiB
    short* w2b   = (short*)(ws + 15204352);        // 512 KiB
    short* w2t   = (short*)(ws + 15728640);        // 512 KiB
    float* dv    = (float*)(ws + 16252928);        // 64 KiB
    short* e0    = (short*)(ws + 16318464);        // 20 MiB (frag E, ping)
    short* e1    = (short*)(ws + 37289984);        // 20 MiB (frag E, pong)
    // total 58261504 B ~= 55.6 MiB (fit verified by R11 run)

    // Host-side threefry key derivation (partitionable semantics):
    //   fk_i = tf((0,42),(0,i));  k2_i = tf(fk_i,(0,1))
    Keys4 keys;
    for (uint32_t i = 0; i < 4; ++i) {
        uint32_t f0, f1, g0, g1;
        tf2x32(0u, 42u, 0u, i, f0, f1);
        tf2x32(f0, f1, 0u, 1u, g0, g1);
        keys.a[i] = g0;
        keys.b[i] = g1;
    }

    // 1851392 prep items + 1310720 E0 slots = 3162112 = 12352*256
    k_prep<<<12352, 256, 0, stream>>>(x, W1, W2, w1t, w2b, w2t, zb, dv,
                                      e0, keys.a[0], keys.b[0]);

    const float tvals[4] = {0.0f, 0.5f, 0.5f, 1.0f};
    const float cnext[4] = {0.5f, 0.5f, 1.0f, 0.0f};  // Zb_{s+1} = x + cnext*fz_s
    const float cw[4]    = {1.0f, 2.0f, 2.0f, 1.0f};  // RK4 weights
    for (int s = 0; s < 4; ++s) {
        const int last = (s == 3);
        short* ecur = (s & 1) ? e1 : e0;
        short* enxt = (s & 1) ? e0 : e1;
        k_pre_div<<<dim3(64, 16), 256, 0, stream>>>(
            zb, w1t, w2b, W1, b1, tvals[s], ecur,
            hb, dv + (size_t)s * BATCH,
            enxt, last ? 0u : keys.a[s + 1], last ? 0u : keys.b[s + 1],
            last ? 0 : 1);
        k_fz2<<<256, 256, 0, stream>>>(hb, w2t, b2, x, rksum,
                                       cw[s], (s == 0) ? 1 : 0,
                                       cnext[s], (s < 3) ? 1 : 0, zb);
    }
    int tot = BATCH * (DIMD + 1);
    k_out<<<(tot + 255) / 256, 256, 0, stream>>>(x, rksum, dv, out);
}